// Round 5
// baseline (430.599 us; speedup 1.0000x reference)
//
#include <hip/hip_runtime.h>
#include <stdint.h>

// Link predictor: score[e] = MLP([src,dst,src*dst,|src-dst|]) over 500K edges.
// Round 8: round-7 kernel (passed, link_kernel 159us) + two isolated fixes:
//  - Fix A: __launch_bounds__(256,5). VGPR_Count=56 fits far under the ~102
//    cap; 32KB LDS x5 = 160KB exactly -> 5 blocks/CU = 20 waves (62.5% static
//    vs 50%). Kernel is latency-bound (Mfma 19.5 / VALU 29 / HBM 20 / occ 41,
//    all low) -> more resident gathers = more latency cover.
//  - Fix B: derive phase re-addressed to the GEMM's proven zero-conflict
//    diagonal pattern (wave owns rows w*16+ln15, chunk (ks4*4+quad)^ln15).
//    Round-7's row-sharing pattern (4 lanes/row) measured 3.0M bank-conflict
//    cycles; round-3's GEMM pattern measured exactly 0.
// Everything else byte-identical to round 7.
// d_ws: stage1 = W1 bf16 B-frag layout (65536 shorts), stage2 = W2 (8192 shorts).

typedef __bf16 bf16x8 __attribute__((ext_vector_type(8)));
typedef __bf16 bf16x4 __attribute__((ext_vector_type(4)));
typedef float  f32x4  __attribute__((ext_vector_type(4)));

__device__ __forceinline__ short f2bf(float f) {
    union { float f; uint32_t u; } v; v.f = f;
    uint32_t u = v.u;
    uint32_t r = (u + 0x7fffu + ((u >> 16) & 1u)) >> 16;   // RNE
    return (short)r;
}

// ---------------- prep: W1/W2 fp32 -> bf16 B-fragment layout ----------------
// stage1[((ntile*16+kstep)*64+lane)*8+j] = bf16(W1[k*128+n]),
//   k = kstep*32 + (lane>>4)*8 + j, n = ntile*16 + (lane&15).
// kstep 0..3 = s rows of W1, 4..7 = d, 8..11 = it, 12..15 = df.
__global__ void prep_kernel(const float* __restrict__ W1, const float* __restrict__ W2,
                            short* __restrict__ stage1, short* __restrict__ stage2) {
    int idx = blockIdx.x * 256 + threadIdx.x;
    if (idx < 65536) {
        int k = idx >> 7, n = idx & 127;
        float v = W1[idx];
        int ntile = n >> 4, ln = n & 15;
        int kstep = k >> 5, kr = k & 31;
        int lane = (kr >> 3) * 16 + ln;
        int j = kr & 7;
        stage1[(((ntile * 16 + kstep) * 64 + lane) << 3) + j] = f2bf(v);
    } else if (idx < 65536 + 8192) {
        int i2 = idx - 65536;
        int k = i2 >> 6, n = i2 & 63;
        float v = W2[i2];
        int ntile = n >> 4, ln = n & 15;
        int kstep = k >> 5, kr = k & 31;
        int lane = (kr >> 3) * 16 + ln;
        int j = kr & 7;
        stage2[(((ntile * 4 + kstep) * 64 + lane) << 3) + j] = f2bf(v);
    }
}

// ---------------- main ----------------
// 64 edges/block, 256 threads (4 waves), 32KB LDS.
// LDS: s-tile [64 x 128]bf16 at 0 (stride 256B), d-tile at 16384.
//   16B chunk cc = k>>3 stored at physical chunk cc ^ (m&15) (XOR swizzle).
// After GEMM1a: s-tile overwritten in place with it, d-tile with df.
// After GEMM1b: [0,16384) reused for h1 bf16 [64x128] (same swizzle).
// After GEMM2: [0,17408) holds h2 fp32 [64 x 68] (stride 272B).
__launch_bounds__(256, 5)
__global__ void link_kernel(const float* __restrict__ z,
                            const int*   __restrict__ ei,
                            const float* __restrict__ b1,
                            const float* __restrict__ b2,
                            const float* __restrict__ w3,
                            const float* __restrict__ b3,
                            const short* __restrict__ stage1,
                            const short* __restrict__ stage2,
                            float* __restrict__ out,
                            int E) {
    __shared__ __align__(16) char smem[32768];

    const int tid  = threadIdx.x;
    const int lane = tid & 63;
    const int wave = tid >> 6;
    const int ln15 = lane & 15;
    const int quad = lane >> 4;
    const int e0   = blockIdx.x * 64;

    // ---- Phase A: gather src/dst rows -> LDS bf16 (swizzled) ----
    // Each thread: fixed float4-chunk c = tid&31; rows m = (tid>>5) + 8i.
    const int c    = tid & 31;
    const int mrow = tid >> 5;
    int si[8], di[8];
    #pragma unroll
    for (int i = 0; i < 8; ++i) {
        int eg = e0 + mrow + i * 8;
        int egc = eg < E ? eg : (E - 1);
        si[i] = ei[egc];
        di[i] = ei[E + egc];
    }
    const int cc   = c >> 1;
    const int half = c & 1;
    #pragma unroll
    for (int i = 0; i < 8; ++i) {
        int m = mrow + i * 8;
        f32x4 s = *(const f32x4*)(z + (size_t)si[i] * 128 + c * 4);
        f32x4 d = *(const f32x4*)(z + (size_t)di[i] * 128 + c * 4);
        int addr = m * 256 + ((cc ^ (m & 15)) << 4) + half * 8;
        bf16x4 ps, pd;
        #pragma unroll
        for (int j = 0; j < 4; ++j) { ps[j] = (__bf16)s[j]; pd[j] = (__bf16)d[j]; }
        *(bf16x4*)(smem + addr)         = ps;
        *(bf16x4*)(smem + 16384 + addr) = pd;
    }
    __syncthreads();

    // ---- GEMM1a: acc += s@W1s + d@W1d. Wave owns n-tiles wave*2, wave*2+1. ----
    f32x4 acc[4][2];
    #pragma unroll
    for (int mt = 0; mt < 4; ++mt)
        #pragma unroll
        for (int nt = 0; nt < 2; ++nt)
            acc[mt][nt] = (f32x4){0.f, 0.f, 0.f, 0.f};

    #pragma unroll
    for (int ks4 = 0; ks4 < 4; ++ks4) {
        bf16x8 Bs[2], Bd[2];
        #pragma unroll
        for (int nt = 0; nt < 2; ++nt) {
            int ntile = wave * 2 + nt;
            Bs[nt] = *(const bf16x8*)(stage1 + (((ntile * 16 + 0 + ks4) * 64 + lane) << 3));
            Bd[nt] = *(const bf16x8*)(stage1 + (((ntile * 16 + 4 + ks4) * 64 + lane) << 3));
        }
        #pragma unroll
        for (int mt = 0; mt < 4; ++mt) {
            int m = mt * 16 + ln15;
            int off = m * 256 + (((ks4 * 4 + quad) ^ (m & 15)) << 4);
            bf16x8 sf = *(const bf16x8*)(smem + off);
            bf16x8 df = *(const bf16x8*)(smem + 16384 + off);
            #pragma unroll
            for (int nt = 0; nt < 2; ++nt) {
                acc[mt][nt] = __builtin_amdgcn_mfma_f32_16x16x32_bf16(sf, Bs[nt], acc[mt][nt], 0, 0, 0);
                acc[mt][nt] = __builtin_amdgcn_mfma_f32_16x16x32_bf16(df, Bd[nt], acc[mt][nt], 0, 0, 0);
            }
        }
    }
    __syncthreads();   // all waves done reading s,d

    // ---- derive ONCE: it -> s-region, df -> d-region (in place) ----
    // Wave w owns rows w*16+ln15; chunk slot (ks4*4+quad)^ln15 — the exact
    // diagonal addressing GEMM1a uses (measured 0 bank conflicts), vs round-7's
    // 4-lanes-per-row pattern (measured 3.0M conflict cycles).
    {
        int mder = wave * 16 + ln15;    // mder & 15 == ln15
        #pragma unroll
        for (int ks4 = 0; ks4 < 4; ++ks4) {
            int addr = mder * 256 + (((ks4 * 4 + quad) ^ ln15) << 4);
            bf16x8 s = *(const bf16x8*)(smem + addr);
            bf16x8 d = *(const bf16x8*)(smem + 16384 + addr);
            bf16x8 it, dd;
            #pragma unroll
            for (int j = 0; j < 8; ++j) {
                float fs = (float)s[j], fd = (float)d[j];
                it[j] = (__bf16)(fs * fd);
                dd[j] = (__bf16)__builtin_fabsf(fs - fd);
            }
            *(bf16x8*)(smem + addr)         = it;
            *(bf16x8*)(smem + 16384 + addr) = dd;
        }
    }
    __syncthreads();

    // ---- GEMM1b: acc += it@W1it + df@W1df ----
    #pragma unroll
    for (int ks4 = 0; ks4 < 4; ++ks4) {
        bf16x8 Bi[2], Bf[2];
        #pragma unroll
        for (int nt = 0; nt < 2; ++nt) {
            int ntile = wave * 2 + nt;
            Bi[nt] = *(const bf16x8*)(stage1 + (((ntile * 16 +  8 + ks4) * 64 + lane) << 3));
            Bf[nt] = *(const bf16x8*)(stage1 + (((ntile * 16 + 12 + ks4) * 64 + lane) << 3));
        }
        #pragma unroll
        for (int mt = 0; mt < 4; ++mt) {
            int m = mt * 16 + ln15;
            int off = m * 256 + (((ks4 * 4 + quad) ^ (m & 15)) << 4);
            bf16x8 itf = *(const bf16x8*)(smem + off);
            bf16x8 ddf = *(const bf16x8*)(smem + 16384 + off);
            #pragma unroll
            for (int nt = 0; nt < 2; ++nt) {
                acc[mt][nt] = __builtin_amdgcn_mfma_f32_16x16x32_bf16(itf, Bi[nt], acc[mt][nt], 0, 0, 0);
                acc[mt][nt] = __builtin_amdgcn_mfma_f32_16x16x32_bf16(ddf, Bf[nt], acc[mt][nt], 0, 0, 0);
            }
        }
    }
    __syncthreads();   // all waves done reading it,df

    // ---- epilogue 1: h1 = relu(acc + b1) -> LDS bf16 [64 x 128] at 0, swizzled ----
    #pragma unroll
    for (int nt = 0; nt < 2; ++nt) {
        int n = (wave * 2 + nt) * 16 + ln15;      // = k2 for GEMM2
        float bias = b1[n];
        #pragma unroll
        for (int mt = 0; mt < 4; ++mt) {
            #pragma unroll
            for (int r = 0; r < 4; ++r) {
                int row = mt * 16 + quad * 4 + r;  // C/D: row = quad*4 + reg
                float h = acc[mt][nt][r] + bias;
                h = h > 0.f ? h : 0.f;
                int addr = row * 256 + (((n >> 3) ^ (row & 15)) << 4) + (n & 7) * 2;
                *(short*)(smem + addr) = f2bf(h);
            }
        }
    }
    __syncthreads();

    // ---- GEMM2: h1[64x128] @ W2[128x64]; wave w owns n-tile w (16 cols) ----
    f32x4 acc2[4];
    #pragma unroll
    for (int mt = 0; mt < 4; ++mt) acc2[mt] = (f32x4){0.f, 0.f, 0.f, 0.f};

    #pragma unroll
    for (int ks = 0; ks < 4; ++ks) {
        bf16x8 b = *(const bf16x8*)(stage2 + (((wave * 4 + ks) * 64 + lane) << 3));
        #pragma unroll
        for (int mt = 0; mt < 4; ++mt) {
            int m = mt * 16 + ln15;
            int ccr = ks * 4 + quad;
            bf16x8 a = *(const bf16x8*)(smem + m * 256 + ((ccr ^ (m & 15)) << 4));
            acc2[mt] = __builtin_amdgcn_mfma_f32_16x16x32_bf16(a, b, acc2[mt], 0, 0, 0);
        }
    }
    __syncthreads();   // all waves done reading h1

    // ---- epilogue 2: h2 = relu(acc2 + b2) -> LDS fp32 [64 x 68] at 0 ----
    {
        int n2 = wave * 16 + ln15;
        float bias = b2[n2];
        #pragma unroll
        for (int mt = 0; mt < 4; ++mt) {
            #pragma unroll
            for (int r = 0; r < 4; ++r) {
                int row = mt * 16 + quad * 4 + r;
                float h = acc2[mt][r] + bias;
                h = h > 0.f ? h : 0.f;
                *(float*)(smem + row * 272 + n2 * 4) = h;
            }
        }
    }
    __syncthreads();

    // ---- final: score = h2 . W3 + b3 (fp32), wave 0, one lane per edge ----
    if (wave == 0) {
        int e = lane;
        float accf = b3[0];
        const float* h2p = (const float*)(smem + e * 272);
        #pragma unroll
        for (int kk = 0; kk < 16; ++kk) {
            f32x4 h = *(const f32x4*)(h2p + kk * 4);
            f32x4 w = *(const f32x4*)(w3 + kk * 4);
            accf += h[0] * w[0] + h[1] * w[1] + h[2] * w[2] + h[3] * w[3];
        }
        if (e0 + e < E) out[e0 + e] = accf;
    }
}

extern "C" void kernel_launch(void* const* d_in, const int* in_sizes, int n_in,
                              void* d_out, int out_size, void* d_ws, size_t ws_size,
                              hipStream_t stream) {
    const float* z  = (const float*)d_in[0];
    const int*   ei = (const int*)  d_in[1];
    const float* W1 = (const float*)d_in[2];
    const float* b1 = (const float*)d_in[3];
    const float* W2 = (const float*)d_in[4];
    const float* b2 = (const float*)d_in[5];
    const float* W3 = (const float*)d_in[6];
    const float* b3 = (const float*)d_in[7];
    float* out = (float*)d_out;

    int E = in_sizes[1] / 2;

    short* stage1 = (short*)d_ws;          // 65536 shorts = 128 KB
    short* stage2 = stage1 + 65536;        // 8192 shorts  = 16 KB

    prep_kernel<<<288, 256, 0, stream>>>(W1, W2, stage1, stage2);

    int nblk = (E + 63) / 64;
    link_kernel<<<nblk, 256, 0, stream>>>(z, ei, b1, b2, W3, b3, stage1, stage2, out, E);
}

// Round 7
// 415.289 us; speedup vs baseline: 1.0369x; 1.0369x over previous
//
#include <hip/hip_runtime.h>
#include <stdint.h>

// Link predictor: score[e] = MLP([src,dst,src*dst,|src-dst|]) over 500K edges.
// Round 10: round-8 passing source with two deltas:
//  - __launch_bounds__ back to (256,4): round-8's (256,5) squeezed VGPR 56->48
//    and cost 17us (gather concurrency), with occupancy unchanged at 42% (the
//    5th 32KB block never co-scheduled). Measured regression, reverted.
//  - gather phase restructured: all 16 f32x4 row-loads issued into sv[]/dv[]
//    register arrays in one batch loop, converted/stored to LDS in a second
//    loop. No scheduling intrinsics (round-9's sched_barrier(0) build never
//    ran: container failed twice; exotic elements correlate with harness
//    failures this session). Goal: more gather loads in flight (round-7
//    VGPR=56 at cap 128 => only ~4-6 outstanding; kernel is latency-bound,
//    all utils <45%).
//  - keep round-8 Fix B: zero-conflict derive addressing (3.0M -> 0 measured).
// VGPR_Count is the diagnostic: ~100 => hoist held (expect ~135-150us);
// ~56 => loads sank anyway (expect ~155us, = round 7 minus conflicts).
// d_ws: stage1 = W1 bf16 B-frag layout (65536 shorts), stage2 = W2 (8192 shorts).

typedef __bf16 bf16x8 __attribute__((ext_vector_type(8)));
typedef __bf16 bf16x4 __attribute__((ext_vector_type(4)));
typedef float  f32x4  __attribute__((ext_vector_type(4)));

__device__ __forceinline__ short f2bf(float f) {
    union { float f; uint32_t u; } v; v.f = f;
    uint32_t u = v.u;
    uint32_t r = (u + 0x7fffu + ((u >> 16) & 1u)) >> 16;   // RNE
    return (short)r;
}

// ---------------- prep: W1/W2 fp32 -> bf16 B-fragment layout ----------------
// stage1[((ntile*16+kstep)*64+lane)*8+j] = bf16(W1[k*128+n]),
//   k = kstep*32 + (lane>>4)*8 + j, n = ntile*16 + (lane&15).
// kstep 0..3 = s rows of W1, 4..7 = d, 8..11 = it, 12..15 = df.
__global__ void prep_kernel(const float* __restrict__ W1, const float* __restrict__ W2,
                            short* __restrict__ stage1, short* __restrict__ stage2) {
    int idx = blockIdx.x * 256 + threadIdx.x;
    if (idx < 65536) {
        int k = idx >> 7, n = idx & 127;
        float v = W1[idx];
        int ntile = n >> 4, ln = n & 15;
        int kstep = k >> 5, kr = k & 31;
        int lane = (kr >> 3) * 16 + ln;
        int j = kr & 7;
        stage1[(((ntile * 16 + kstep) * 64 + lane) << 3) + j] = f2bf(v);
    } else if (idx < 65536 + 8192) {
        int i2 = idx - 65536;
        int k = i2 >> 6, n = i2 & 63;
        float v = W2[i2];
        int ntile = n >> 4, ln = n & 15;
        int kstep = k >> 5, kr = k & 31;
        int lane = (kr >> 3) * 16 + ln;
        int j = kr & 7;
        stage2[(((ntile * 4 + kstep) * 64 + lane) << 3) + j] = f2bf(v);
    }
}

// ---------------- main ----------------
// 64 edges/block, 256 threads (4 waves), 32KB LDS.
// LDS: s-tile [64 x 128]bf16 at 0 (stride 256B), d-tile at 16384.
//   16B chunk cc = k>>3 stored at physical chunk cc ^ (m&15) (XOR swizzle).
// After GEMM1a: s-tile overwritten in place with it, d-tile with df.
// After GEMM1b: [0,16384) reused for h1 bf16 [64x128] (same swizzle).
// After GEMM2: [0,17408) holds h2 fp32 [64 x 68] (stride 272B).
__launch_bounds__(256, 4)
__global__ void link_kernel(const float* __restrict__ z,
                            const int*   __restrict__ ei,
                            const float* __restrict__ b1,
                            const float* __restrict__ b2,
                            const float* __restrict__ w3,
                            const float* __restrict__ b3,
                            const short* __restrict__ stage1,
                            const short* __restrict__ stage2,
                            float* __restrict__ out,
                            int E) {
    __shared__ __align__(16) char smem[32768];

    const int tid  = threadIdx.x;
    const int lane = tid & 63;
    const int wave = tid >> 6;
    const int ln15 = lane & 15;
    const int quad = lane >> 4;
    const int e0   = blockIdx.x * 64;

    // ---- Phase A: gather src/dst rows -> LDS bf16 (swizzled) ----
    // Each thread: fixed float4-chunk c = tid&31; rows m = (tid>>5) + 8i.
    // Batch structure: issue all 16 f32x4 loads into register arrays first,
    // then convert+store. (Separation invites the scheduler to keep them
    // all in flight; no intrinsics used.)
    const int c    = tid & 31;
    const int mrow = tid >> 5;
    int si[8], di[8];
    #pragma unroll
    for (int i = 0; i < 8; ++i) {
        int eg = e0 + mrow + i * 8;
        int egc = eg < E ? eg : (E - 1);
        si[i] = ei[egc];
        di[i] = ei[E + egc];
    }
    f32x4 sv[8], dv[8];
    #pragma unroll
    for (int i = 0; i < 8; ++i) {
        sv[i] = *(const f32x4*)(z + (size_t)si[i] * 128 + c * 4);
        dv[i] = *(const f32x4*)(z + (size_t)di[i] * 128 + c * 4);
    }
    const int cc   = c >> 1;
    const int half = c & 1;
    #pragma unroll
    for (int i = 0; i < 8; ++i) {
        int m = mrow + i * 8;
        int addr = m * 256 + ((cc ^ (m & 15)) << 4) + half * 8;
        bf16x4 ps, pd;
        #pragma unroll
        for (int j = 0; j < 4; ++j) { ps[j] = (__bf16)sv[i][j]; pd[j] = (__bf16)dv[i][j]; }
        *(bf16x4*)(smem + addr)         = ps;
        *(bf16x4*)(smem + 16384 + addr) = pd;
    }
    __syncthreads();

    // ---- GEMM1a: acc += s@W1s + d@W1d. Wave owns n-tiles wave*2, wave*2+1. ----
    f32x4 acc[4][2];
    #pragma unroll
    for (int mt = 0; mt < 4; ++mt)
        #pragma unroll
        for (int nt = 0; nt < 2; ++nt)
            acc[mt][nt] = (f32x4){0.f, 0.f, 0.f, 0.f};

    #pragma unroll
    for (int ks4 = 0; ks4 < 4; ++ks4) {
        bf16x8 Bs[2], Bd[2];
        #pragma unroll
        for (int nt = 0; nt < 2; ++nt) {
            int ntile = wave * 2 + nt;
            Bs[nt] = *(const bf16x8*)(stage1 + (((ntile * 16 + 0 + ks4) * 64 + lane) << 3));
            Bd[nt] = *(const bf16x8*)(stage1 + (((ntile * 16 + 4 + ks4) * 64 + lane) << 3));
        }
        #pragma unroll
        for (int mt = 0; mt < 4; ++mt) {
            int m = mt * 16 + ln15;
            int off = m * 256 + (((ks4 * 4 + quad) ^ (m & 15)) << 4);
            bf16x8 sf = *(const bf16x8*)(smem + off);
            bf16x8 df = *(const bf16x8*)(smem + 16384 + off);
            #pragma unroll
            for (int nt = 0; nt < 2; ++nt) {
                acc[mt][nt] = __builtin_amdgcn_mfma_f32_16x16x32_bf16(sf, Bs[nt], acc[mt][nt], 0, 0, 0);
                acc[mt][nt] = __builtin_amdgcn_mfma_f32_16x16x32_bf16(df, Bd[nt], acc[mt][nt], 0, 0, 0);
            }
        }
    }
    __syncthreads();   // all waves done reading s,d

    // ---- derive ONCE: it -> s-region, df -> d-region (in place) ----
    // Zero-conflict diagonal addressing (validated round 8: 3.0M -> 0):
    // wave w owns rows w*16+ln15; chunk slot (ks4*4+quad)^ln15.
    {
        int mder = wave * 16 + ln15;    // mder & 15 == ln15
        #pragma unroll
        for (int ks4 = 0; ks4 < 4; ++ks4) {
            int addr = mder * 256 + (((ks4 * 4 + quad) ^ ln15) << 4);
            bf16x8 s = *(const bf16x8*)(smem + addr);
            bf16x8 d = *(const bf16x8*)(smem + 16384 + addr);
            bf16x8 it, dd;
            #pragma unroll
            for (int j = 0; j < 8; ++j) {
                float fs = (float)s[j], fd = (float)d[j];
                it[j] = (__bf16)(fs * fd);
                dd[j] = (__bf16)__builtin_fabsf(fs - fd);
            }
            *(bf16x8*)(smem + addr)         = it;
            *(bf16x8*)(smem + 16384 + addr) = dd;
        }
    }
    __syncthreads();

    // ---- GEMM1b: acc += it@W1it + df@W1df ----
    #pragma unroll
    for (int ks4 = 0; ks4 < 4; ++ks4) {
        bf16x8 Bi[2], Bf[2];
        #pragma unroll
        for (int nt = 0; nt < 2; ++nt) {
            int ntile = wave * 2 + nt;
            Bi[nt] = *(const bf16x8*)(stage1 + (((ntile * 16 +  8 + ks4) * 64 + lane) << 3));
            Bf[nt] = *(const bf16x8*)(stage1 + (((ntile * 16 + 12 + ks4) * 64 + lane) << 3));
        }
        #pragma unroll
        for (int mt = 0; mt < 4; ++mt) {
            int m = mt * 16 + ln15;
            int off = m * 256 + (((ks4 * 4 + quad) ^ (m & 15)) << 4);
            bf16x8 itf = *(const bf16x8*)(smem + off);
            bf16x8 ddf = *(const bf16x8*)(smem + 16384 + off);
            #pragma unroll
            for (int nt = 0; nt < 2; ++nt) {
                acc[mt][nt] = __builtin_amdgcn_mfma_f32_16x16x32_bf16(itf, Bi[nt], acc[mt][nt], 0, 0, 0);
                acc[mt][nt] = __builtin_amdgcn_mfma_f32_16x16x32_bf16(ddf, Bf[nt], acc[mt][nt], 0, 0, 0);
            }
        }
    }
    __syncthreads();   // all waves done reading it,df

    // ---- epilogue 1: h1 = relu(acc + b1) -> LDS bf16 [64 x 128] at 0, swizzled ----
    #pragma unroll
    for (int nt = 0; nt < 2; ++nt) {
        int n = (wave * 2 + nt) * 16 + ln15;      // = k2 for GEMM2
        float bias = b1[n];
        #pragma unroll
        for (int mt = 0; mt < 4; ++mt) {
            #pragma unroll
            for (int r = 0; r < 4; ++r) {
                int row = mt * 16 + quad * 4 + r;  // C/D: row = quad*4 + reg
                float h = acc[mt][nt][r] + bias;
                h = h > 0.f ? h : 0.f;
                int addr = row * 256 + (((n >> 3) ^ (row & 15)) << 4) + (n & 7) * 2;
                *(short*)(smem + addr) = f2bf(h);
            }
        }
    }
    __syncthreads();

    // ---- GEMM2: h1[64x128] @ W2[128x64]; wave w owns n-tile w (16 cols) ----
    f32x4 acc2[4];
    #pragma unroll
    for (int mt = 0; mt < 4; ++mt) acc2[mt] = (f32x4){0.f, 0.f, 0.f, 0.f};

    #pragma unroll
    for (int ks = 0; ks < 4; ++ks) {
        bf16x8 b = *(const bf16x8*)(stage2 + (((wave * 4 + ks) * 64 + lane) << 3));
        #pragma unroll
        for (int mt = 0; mt < 4; ++mt) {
            int m = mt * 16 + ln15;
            int ccr = ks * 4 + quad;
            bf16x8 a = *(const bf16x8*)(smem + m * 256 + ((ccr ^ (m & 15)) << 4));
            acc2[mt] = __builtin_amdgcn_mfma_f32_16x16x32_bf16(a, b, acc2[mt], 0, 0, 0);
        }
    }
    __syncthreads();   // all waves done reading h1

    // ---- epilogue 2: h2 = relu(acc2 + b2) -> LDS fp32 [64 x 68] at 0 ----
    {
        int n2 = wave * 16 + ln15;
        float bias = b2[n2];
        #pragma unroll
        for (int mt = 0; mt < 4; ++mt) {
            #pragma unroll
            for (int r = 0; r < 4; ++r) {
                int row = mt * 16 + quad * 4 + r;
                float h = acc2[mt][r] + bias;
                h = h > 0.f ? h : 0.f;
                *(float*)(smem + row * 272 + n2 * 4) = h;
            }
        }
    }
    __syncthreads();

    // ---- final: score = h2 . W3 + b3 (fp32), wave 0, one lane per edge ----
    if (wave == 0) {
        int e = lane;
        float accf = b3[0];
        const float* h2p = (const float*)(smem + e * 272);
        #pragma unroll
        for (int kk = 0; kk < 16; ++kk) {
            f32x4 h = *(const f32x4*)(h2p + kk * 4);
            f32x4 w = *(const f32x4*)(w3 + kk * 4);
            accf += h[0] * w[0] + h[1] * w[1] + h[2] * w[2] + h[3] * w[3];
        }
        if (e0 + e < E) out[e0 + e] = accf;
    }
}

extern "C" void kernel_launch(void* const* d_in, const int* in_sizes, int n_in,
                              void* d_out, int out_size, void* d_ws, size_t ws_size,
                              hipStream_t stream) {
    const float* z  = (const float*)d_in[0];
    const int*   ei = (const int*)  d_in[1];
    const float* W1 = (const float*)d_in[2];
    const float* b1 = (const float*)d_in[3];
    const float* W2 = (const float*)d_in[4];
    const float* b2 = (const float*)d_in[5];
    const float* W3 = (const float*)d_in[6];
    const float* b3 = (const float*)d_in[7];
    float* out = (float*)d_out;

    int E = in_sizes[1] / 2;

    short* stage1 = (short*)d_ws;          // 65536 shorts = 128 KB
    short* stage2 = stage1 + 65536;        // 8192 shorts  = 16 KB

    prep_kernel<<<288, 256, 0, stream>>>(W1, W2, stage1, stage2);

    int nblk = (E + 63) / 64;
    link_kernel<<<nblk, 256, 0, stream>>>(z, ei, b1, b2, W3, b3, stage1, stage2, out, E);
}